// Round 13
// baseline (252.291 us; speedup 1.0000x reference)
//
#include <hip/hip_runtime.h>
#include <hip/hip_fp16.h>

#define HID 64
#define ELLK 32   // slots/node; kept degree ~Poisson(5.5), max over 100k ~18
#define CUT_D2 132.5471f   // drop rbf < 1e-5 (R10: measured no absmax change)
#define LDSP 17   // LDS transpose pitch in dwords (16 nodes + 1 pad)

typedef _Float16 half8 __attribute__((ext_vector_type(8)));
typedef float f32x4 __attribute__((ext_vector_type(4)));

__device__ __forceinline__ float rbf_of(unsigned w) {
    return __half2float(__ushort_as_half((unsigned short)(w & 0x7fff)));
}

// x16[n][h] = fp16(emb[z[n]][h]); also zeroes ELL counters (rides this kernel).
__global__ void embed_kernel(const int* __restrict__ z, const float* __restrict__ emb,
                             __half* __restrict__ x16, int* __restrict__ cnt, int n) {
    int t = blockIdx.x * blockDim.x + threadIdx.x;
    if (t <= n) cnt[t] = 0;
    if (t >= n * HID / 2) return;
    int node = t >> 5, h2 = (t & 31) * 2;
    const float* src = emb + z[node] * HID + h2;
    __half2 v;
    v.x = __float2half(src[0]);
    v.y = __float2half(src[1]);
    *(__half2*)(x16 + (size_t)node * HID + h2) = v;
}

// ELL fill + fused rbf for KEPT edges; packed record (col<<15)|fp16(rbf).
__global__ void fill_kernel(const int* __restrict__ row, const int* __restrict__ col,
                            const float* __restrict__ pos, int* __restrict__ cnt,
                            unsigned* __restrict__ ell, int e) {
    int t = blockIdx.x * blockDim.x + threadIdx.x;
    if (t >= e) return;
    int r = row[t], c = col[t];
    float dx = pos[3 * r]     - pos[3 * c];
    float dy = pos[3 * r + 1] - pos[3 * c + 1];
    float dz = pos[3 * r + 2] - pos[3 * c + 2];
    float d2 = dx * dx + dy * dy + dz * dz;
    if (d2 > CUT_D2) return;
    float rbf = expf(-sqrtf(d2));
    unsigned short hb = __half_as_ushort(__float2half(rbf));
    int p = atomicAdd(&cnt[r], 1);
    if (p < ELLK) ell[(size_t)r * ELLK + p] = ((unsigned)c << 15) | (unsigned)hb;
}

// FUSED layer: gather (ELL, 2 nodes/pair, lane=h) for a 16-node tile, transpose
// y through a PER-WAVE 4.3KB fp32 LDS buffer, then the verified MFMA linear.
// R6-fusion lesson addressed: MFMA (not 64 shfl/node) epilogue + small LDS +
// launch_bounds keep occupancy high; linear's compute hides in gather bubbles.
// fp32 acc -> RNE fp16 A-frag = same rounding as R12's y16 store/load ->
// bit-identical results. No __syncthreads: LDS buffer is wave-private.
__global__ __launch_bounds__(256, 6)
void layer_kernel(const __half* __restrict__ x16, const int* __restrict__ cnt,
                  const unsigned* __restrict__ ell, const float* __restrict__ W,
                  const float* __restrict__ b, float* __restrict__ out32,
                  __half* __restrict__ out16, int n) {
    __shared__ float ytr[4][HID * LDSP];
    int tid = threadIdx.x;
    int lane = tid & 63;
    int wia = tid >> 6;
    int r16 = lane & 15, quad = lane >> 4;

    half8 bfrag[4][2];
    float biasv[4];
#pragma unroll
    for (int ht = 0; ht < 4; ++ht) {
#pragma unroll
        for (int kt = 0; kt < 2; ++kt) {
            const float* src = W + (ht * 16 + r16) * HID + kt * 32 + quad * 8;
            half8 h;
#pragma unroll
            for (int j = 0; j < 8; ++j) h[j] = (_Float16)src[j];
            bfrag[ht][kt] = h;
        }
        biasv[ht] = b[ht * 16 + r16];
    }

    float* my = ytr[wia];
    int wid = (blockIdx.x << 2) + wia;
    int nw = gridDim.x << 2;
    int ntiles = (n + 15) >> 4;
    for (int t = wid; t < ntiles; t += nw) {
        int base = t << 4;
        // ---- gather phase: 8 node-pairs (lane = h) ----
#pragma unroll
        for (int pp = 0; pp < 8; ++pp) {
            int n0 = base + pp * 2;
            int m0 = (n0 < n) ? n0 : (n - 1);          // tail clamp (stores masked later)
            int m1 = (n0 + 1 < n) ? (n0 + 1) : (n - 1);
            int c0 = cnt[m0]; if (c0 > ELLK) c0 = ELLK;
            int c1 = cnt[m1]; if (c1 > ELLK) c1 = ELLK;
            unsigned rec = ell[(size_t)m0 * ELLK + lane];  // lanes 0-31: m0, 32-63: m0+1
            float acc0 = __half2float(x16[(size_t)m0 * HID + lane]);
            float acc1 = __half2float(x16[(size_t)m1 * HID + lane]);
            int mc = c0 > c1 ? c0 : c1;                // wave-uniform
            for (int j = 0; j < mc; j += 4) {
#pragma unroll
                for (int i = 0; i < 4; ++i) {
                    int s = j + i;
                    unsigned wA = __shfl(rec, s);
                    unsigned wB = __shfl(rec, 32 + s);
                    float vA = __half2float(x16[(wA >> 15) * HID + lane]);
                    float vB = __half2float(x16[(wB >> 15) * HID + lane]);
                    float rA = (s < c0) ? rbf_of(wA) : 0.0f;
                    float rB = (s < c1) ? rbf_of(wB) : 0.0f;
                    acc0 = fmaf(vA, rA, acc0);
                    acc1 = fmaf(vB, rB, acc1);
                }
            }
            // transpose store: [h][node_local], pitch 17 dwords
            // banks: lane*17 (+0/1) mod 32 -> 2-way alias = free (m136)
            my[lane * LDSP + pp * 2]     = acc0;
            my[lane * LDSP + pp * 2 + 1] = acc1;
        }
        // ---- A-frags from LDS (read banks: 2 lanes/bank = free) ----
        half8 afrag0, afrag1;
#pragma unroll
        for (int j = 0; j < 8; ++j) {
            afrag0[j] = (_Float16)my[(quad * 8 + j) * LDSP + r16];
            afrag1[j] = (_Float16)my[(32 + quad * 8 + j) * LDSP + r16];
        }
        // ---- MFMA linear + epilogue (layouts HW-verified) ----
#pragma unroll
        for (int ht = 0; ht < 4; ++ht) {
            f32x4 acc = {biasv[ht], biasv[ht], biasv[ht], biasv[ht]};
            acc = __builtin_amdgcn_mfma_f32_16x16x32_f16(afrag0, bfrag[ht][0], acc, 0, 0, 0);
            acc = __builtin_amdgcn_mfma_f32_16x16x32_f16(afrag1, bfrag[ht][1], acc, 0, 0, 0);
#pragma unroll
            for (int r = 0; r < 4; ++r) {
                int row = base + quad * 4 + r;
                if (row < n) {
                    float v = fmaxf(acc[r], 0.0f);
                    size_t idx = (size_t)row * HID + ht * 16 + r16;
                    if (out32) out32[idx] = v;
                    if (out16) out16[idx] = __float2half(v);
                }
            }
        }
    }
}

extern "C" void kernel_launch(void* const* d_in, const int* in_sizes, int n_in,
                              void* d_out, int out_size, void* d_ws, size_t ws_size,
                              hipStream_t stream) {
    const int*   z    = (const int*)d_in[0];
    const float* pos  = (const float*)d_in[1];
    const int*   eidx = (const int*)d_in[2];
    const float* emb  = (const float*)d_in[3];
    const float* Ws   = (const float*)d_in[4];
    const float* bs   = (const float*)d_in[5];
    int n = in_sizes[0];
    int e = in_sizes[2] / 2;
    int nlayers = in_sizes[4] / (HID * HID);
    const int* row = eidx;
    const int* col = eidx + e;
    float* out = (float*)d_out;

    char* ws = (char*)d_ws;
    __half*   X16 = (__half*)ws;                                     // n*64 fp16 (12.8 MB)
    __half*   X16b = X16 + (size_t)n * HID;                          // ping-pong (12.8 MB)
    unsigned* ell = (unsigned*)((char*)X16b + (size_t)n * HID * 2);  // (n+2)*ELLK u32
    int*      cnt = (int*)((char*)ell + (size_t)(n + 2) * ELLK * 4); // n+1 ints

    int ntiles = (n + 15) >> 4;
    int nblk = (ntiles + 3) / 4;

    // 5 dispatches: embed(+cnt zero), fill, 3x fused layer
    embed_kernel<<<(n * HID / 2 + 255) / 256, 256, 0, stream>>>(z, emb, X16, cnt, n);
    fill_kernel<<<(e + 255) / 256, 256, 0, stream>>>(row, col, pos, cnt, ell, e);

    // layer l reads srcX, writes dstX (fp16) or d_out (fp32, final layer)
    for (int l = 0; l < nlayers; ++l) {
        bool last = (l == nlayers - 1);
        const __half* srcX = (l % 2 == 0) ? X16 : X16b;
        __half*       dstX = (l % 2 == 0) ? X16b : X16;
        layer_kernel<<<nblk, 256, 0, stream>>>(srcX, cnt, ell,
                                               Ws + (size_t)l * HID * HID,
                                               bs + (size_t)l * HID,
                                               last ? out : nullptr,
                                               last ? nullptr : dstX, n);
    }
}

// Round 14
// 236.604 us; speedup vs baseline: 1.0663x; 1.0663x over previous
//
#include <hip/hip_runtime.h>
#include <hip/hip_fp16.h>

#define HID 64
#define ELLK 32   // slots/node; kept degree ~Poisson(5.5), max over 100k ~18
#define CUT_D2 132.5471f   // drop rbf < 1e-5 (R10: measured no absmax change)

typedef _Float16 half8 __attribute__((ext_vector_type(8)));
typedef float f32x4 __attribute__((ext_vector_type(4)));

__device__ __forceinline__ float rbf_of(unsigned w) {
    return __half2float(__ushort_as_half((unsigned short)(w & 0x7fff)));
}

// x16[n][h] = fp16(emb[z[n]][h]); also zeroes ELL counters (rides this kernel).
__global__ void embed_kernel(const int* __restrict__ z, const float* __restrict__ emb,
                             __half* __restrict__ x16, int* __restrict__ cnt, int n) {
    int t = blockIdx.x * blockDim.x + threadIdx.x;
    if (t <= n) cnt[t] = 0;
    if (t >= n * HID / 2) return;
    int node = t >> 5, h2 = (t & 31) * 2;
    const float* src = emb + z[node] * HID + h2;
    __half2 v;
    v.x = __float2half(src[0]);
    v.y = __float2half(src[1]);
    *(__half2*)(x16 + (size_t)node * HID + h2) = v;
}

// ELL fill + fused rbf for KEPT edges; packed record (col<<15)|fp16(rbf).
__global__ void fill_kernel(const int* __restrict__ row, const int* __restrict__ col,
                            const float* __restrict__ pos, int* __restrict__ cnt,
                            unsigned* __restrict__ ell, int e) {
    int t = blockIdx.x * blockDim.x + threadIdx.x;
    if (t >= e) return;
    int r = row[t], c = col[t];
    float dx = pos[3 * r]     - pos[3 * c];
    float dy = pos[3 * r + 1] - pos[3 * c + 1];
    float dz = pos[3 * r + 2] - pos[3 * c + 2];
    float d2 = dx * dx + dy * dy + dz * dz;
    if (d2 > CUT_D2) return;
    float rbf = expf(-sqrtf(d2));
    unsigned short hb = __half_as_ushort(__float2half(rbf));
    int p = atomicAdd(&cnt[r], 1);
    if (p < ELLK) ell[(size_t)r * ELLK + p] = ((unsigned)c << 15) | (unsigned)hb;
}

// y16[n] = fp16( x16[n] + sum_slots x16[col]*rbf ) — TWO nodes per wave,
// R14: SOFTWARE-PIPELINED pair loop. Each pair's serial head (cnt loads ->
// 256B rec load -> residual loads) is issued one iteration EARLY so its
// ~600-cycle latency hides under the previous pair's body (row loads + FMA).
// Same FMA order as R12 -> bit-identical results.
__global__ void gather_kernel(const __half* __restrict__ x16, const int* __restrict__ cnt,
                              const unsigned* __restrict__ ell,
                              __half* __restrict__ y16, int n) {
    int lane = threadIdx.x & 63;
    int wid = (blockIdx.x * blockDim.x + threadIdx.x) >> 6;
    int nw = (gridDim.x * blockDim.x) >> 6;
    int npair = (n + 1) >> 1;
    if (wid >= npair) return;

    // prologue: load state for the first pair
    int p = wid;
    int n0 = __builtin_amdgcn_readfirstlane(2 * p);
    bool two = (n0 + 1 < n);
    int c0 = cnt[n0]; if (c0 > ELLK) c0 = ELLK;
    int c1 = two ? cnt[n0 + 1] : 0; if (c1 > ELLK) c1 = ELLK;
    unsigned rec = ell[(size_t)n0 * ELLK + lane];   // lanes 0-31: n0, 32-63: n0+1
    float acc0 = __half2float(x16[(size_t)n0 * HID + lane]);
    float acc1 = two ? __half2float(x16[((size_t)n0 + 1) * HID + lane]) : 0.0f;

    while (true) {
        // ---- prefetch next pair's head (independent of current body) ----
        int pn = p + nw;
        bool have_next = (pn < npair);
        int nn0 = 0, nc0 = 0, nc1 = 0;
        bool ntwo = false;
        unsigned nrec = 0;
        float nacc0 = 0.0f, nacc1 = 0.0f;
        if (have_next) {
            nn0 = __builtin_amdgcn_readfirstlane(2 * pn);
            ntwo = (nn0 + 1 < n);
            nc0 = cnt[nn0]; if (nc0 > ELLK) nc0 = ELLK;
            nc1 = ntwo ? cnt[nn0 + 1] : 0; if (nc1 > ELLK) nc1 = ELLK;
            nrec = ell[(size_t)nn0 * ELLK + lane];
            nacc0 = __half2float(x16[(size_t)nn0 * HID + lane]);
            nacc1 = ntwo ? __half2float(x16[((size_t)nn0 + 1) * HID + lane]) : 0.0f;
        }
        // ---- body for current pair ----
        int mc = c0 > c1 ? c0 : c1;                 // wave-uniform
        for (int j = 0; j < mc; j += 4) {
#pragma unroll
            for (int i = 0; i < 4; ++i) {
                int s = j + i;                      // < ELLK always
                unsigned wA = __shfl(rec, s);
                unsigned wB = __shfl(rec, 32 + s);
                float vA = __half2float(x16[(wA >> 15) * HID + lane]);
                float vB = __half2float(x16[(wB >> 15) * HID + lane]);
                float rA = (s < c0) ? rbf_of(wA) : 0.0f;
                float rB = (s < c1) ? rbf_of(wB) : 0.0f;
                acc0 = fmaf(vA, rA, acc0);
                acc1 = fmaf(vB, rB, acc1);
            }
        }
        y16[(size_t)n0 * HID + lane] = __float2half(acc0);
        if (two) y16[((size_t)n0 + 1) * HID + lane] = __float2half(acc1);
        if (!have_next) break;
        // ---- rotate pipeline state ----
        p = pn; n0 = nn0; two = ntwo; c0 = nc0; c1 = nc1;
        rec = nrec; acc0 = nacc0; acc1 = nacc1;
    }
}

// MFMA linear (layouts HW-verified): out = relu(Y·Wᵀ + b), 16-node×64-h
// tile/wave, mfma_f32_16x16x32_f16. A-frags load directly from fp16 y16;
// writes fp16 x16 for the next layer; fp32 d_out only on the final layer.
__global__ void linear_kernel(const __half* __restrict__ y16, const float* __restrict__ W,
                              const float* __restrict__ b, float* __restrict__ out32,
                              __half* __restrict__ out16, int n) {
    int lane = threadIdx.x & 63;
    int r16 = lane & 15;
    int quad = lane >> 4;
    int wid = (blockIdx.x * blockDim.x + threadIdx.x) >> 6;
    int nw = (gridDim.x * blockDim.x) >> 6;

    half8 bfrag[4][2];
    float biasv[4];
#pragma unroll
    for (int ht = 0; ht < 4; ++ht) {
#pragma unroll
        for (int kt = 0; kt < 2; ++kt) {
            const float* src = W + (ht * 16 + r16) * HID + kt * 32 + quad * 8;
            half8 h;
#pragma unroll
            for (int j = 0; j < 8; ++j) h[j] = (_Float16)src[j];
            bfrag[ht][kt] = h;
        }
        biasv[ht] = b[ht * 16 + r16];
    }

    int ntiles = (n + 15) >> 4;
    for (int t = wid; t < ntiles; t += nw) {
        int base = t << 4;
        int arow = base + r16;
        if (arow >= n) arow = n - 1;              // tail clamp (loads only)
        const __half* yr = y16 + (size_t)arow * HID + quad * 8;
        half8 afrag0 = *(const half8*)(yr);
        half8 afrag1 = *(const half8*)(yr + 32);
#pragma unroll
        for (int ht = 0; ht < 4; ++ht) {
            f32x4 acc = {biasv[ht], biasv[ht], biasv[ht], biasv[ht]};
            acc = __builtin_amdgcn_mfma_f32_16x16x32_f16(afrag0, bfrag[ht][0], acc, 0, 0, 0);
            acc = __builtin_amdgcn_mfma_f32_16x16x32_f16(afrag1, bfrag[ht][1], acc, 0, 0, 0);
#pragma unroll
            for (int r = 0; r < 4; ++r) {
                int row = base + quad * 4 + r;
                if (row < n) {
                    float v = fmaxf(acc[r], 0.0f);
                    size_t idx = (size_t)row * HID + ht * 16 + r16;
                    if (out32) out32[idx] = v;
                    if (out16) out16[idx] = __float2half(v);
                }
            }
        }
    }
}

extern "C" void kernel_launch(void* const* d_in, const int* in_sizes, int n_in,
                              void* d_out, int out_size, void* d_ws, size_t ws_size,
                              hipStream_t stream) {
    const int*   z    = (const int*)d_in[0];
    const float* pos  = (const float*)d_in[1];
    const int*   eidx = (const int*)d_in[2];
    const float* emb  = (const float*)d_in[3];
    const float* Ws   = (const float*)d_in[4];
    const float* bs   = (const float*)d_in[5];
    int n = in_sizes[0];
    int e = in_sizes[2] / 2;
    int nlayers = in_sizes[4] / (HID * HID);
    const int* row = eidx;
    const int* col = eidx + e;
    float* out = (float*)d_out;

    char* ws = (char*)d_ws;
    __half*   X16 = (__half*)ws;                                   // n*64 fp16 (12.8 MB)
    __half*   Y16 = X16 + (size_t)n * HID;                         // n*64 fp16 (12.8 MB)
    unsigned* ell = (unsigned*)((char*)Y16 + (size_t)n * HID * 2); // (n+2)*ELLK u32
    int*      cnt = (int*)((char*)ell + (size_t)(n + 2) * ELLK * 4); // n+1 ints

    // 8 dispatches: embed(+cnt zero), fill, 3x(gather, linear)
    embed_kernel<<<(n * HID / 2 + 255) / 256, 256, 0, stream>>>(z, emb, X16, cnt, n);
    fill_kernel<<<(e + 255) / 256, 256, 0, stream>>>(row, col, pos, cnt, ell, e);

    for (int l = 0; l < nlayers; ++l) {
        bool last = (l == nlayers - 1);
        gather_kernel<<<2048, 256, 0, stream>>>(X16, cnt, ell, Y16, n);
        linear_kernel<<<1024, 256, 0, stream>>>(Y16, Ws + (size_t)l * HID * HID,
                                                bs + (size_t)l * HID,
                                                last ? out : nullptr,
                                                last ? nullptr : X16, n);
    }
}

// Round 15
// 211.419 us; speedup vs baseline: 1.1933x; 1.1191x over previous
//
#include <hip/hip_runtime.h>
#include <hip/hip_fp16.h>

#define HID 64
#define ELLK 32   // slots/node; kept degree ~Poisson(5.5), max over 100k ~18
#define CUT_D2 132.5471f   // drop rbf < 1e-5 (R10: measured no absmax change)

typedef _Float16 half8 __attribute__((ext_vector_type(8)));
typedef float f32x4 __attribute__((ext_vector_type(4)));

__device__ __forceinline__ float rbf_of(unsigned w) {
    return __half2float(__ushort_as_half((unsigned short)(w & 0x7fff)));
}

// x16[n][h] = fp16(emb[z[n]][h]); also zeroes ELL counters (rides this kernel).
__global__ void embed_kernel(const int* __restrict__ z, const float* __restrict__ emb,
                             __half* __restrict__ x16, int* __restrict__ cnt, int n) {
    int t = blockIdx.x * blockDim.x + threadIdx.x;
    if (t <= n) cnt[t] = 0;
    if (t >= n * HID / 2) return;
    int node = t >> 5, h2 = (t & 31) * 2;
    const float* src = emb + z[node] * HID + h2;
    __half2 v;
    v.x = __float2half(src[0]);
    v.y = __float2half(src[1]);
    *(__half2*)(x16 + (size_t)node * HID + h2) = v;
}

// ELL fill + fused rbf for KEPT edges; packed record (col<<15)|fp16(rbf).
__global__ void fill_kernel(const int* __restrict__ row, const int* __restrict__ col,
                            const float* __restrict__ pos, int* __restrict__ cnt,
                            unsigned* __restrict__ ell, int e) {
    int t = blockIdx.x * blockDim.x + threadIdx.x;
    if (t >= e) return;
    int r = row[t], c = col[t];
    float dx = pos[3 * r]     - pos[3 * c];
    float dy = pos[3 * r + 1] - pos[3 * c + 1];
    float dz = pos[3 * r + 2] - pos[3 * c + 2];
    float d2 = dx * dx + dy * dy + dz * dz;
    if (d2 > CUT_D2) return;
    float rbf = expf(-sqrtf(d2));
    unsigned short hb = __half_as_ushort(__float2half(rbf));
    int p = atomicAdd(&cnt[r], 1);
    if (p < ELLK) ell[(size_t)r * ELLK + p] = ((unsigned)c << 15) | (unsigned)hb;
}

// y16[n] = fp16( x16[n] + sum_slots x16[col]*rbf ) — TWO nodes per wave.
// R15 lane remap: lanes 0-31 own node n0, lanes 32-63 own n0+1, each lane
// covering TWO h-values as __half2 (4 B/lane). Per slot the wave now issues
// ONE bpermute (__shfl with per-lane src (lane&32)+s) + ONE load serving both
// rows (2x128 B), vs 2 shfl + 2 x 2-byte loads in R12 — ~2x fewer hot-loop
// instructions, same rows-in-flight (4 loads cover 8 rows), same traffic.
// Per-h slot order & fp32 FMA order unchanged -> bit-identical to R12.
// (R8/R13/R14 lesson: change NOTHING else — no extra registers, no pipelining.)
__global__ void gather_kernel(const __half* __restrict__ x16, const int* __restrict__ cnt,
                              const unsigned* __restrict__ ell,
                              __half* __restrict__ y16, int n) {
    int lane = threadIdx.x & 63;
    int hsel = lane & 32;              // 0: node n0 lanes, 32: node n0+1 lanes
    int hbase = (lane & 31) * 2;       // h pair handled by this lane
    int wid = (blockIdx.x * blockDim.x + threadIdx.x) >> 6;
    int nw = (gridDim.x * blockDim.x) >> 6;
    int npair = (n + 1) >> 1;
    for (int p = wid; p < npair; p += nw) {
        int n0 = __builtin_amdgcn_readfirstlane(2 * p);
        bool two = (n0 + 1 < n);
        int c0 = cnt[n0]; if (c0 > ELLK) c0 = ELLK;
        int c1 = two ? cnt[n0 + 1] : 0; if (c1 > ELLK) c1 = ELLK;
        int cn = hsel ? c1 : c0;                       // per-lane count
        int myn = (hsel && two) ? (n0 + 1) : n0;       // row owned by this lane
        unsigned rec = ell[(size_t)n0 * ELLK + lane];  // lane = slot (both nodes)
        __half2 res = *(const __half2*)(x16 + (size_t)myn * HID + hbase);
        float accx = __half2float(res.x);
        float accy = __half2float(res.y);
        int mc = c0 > c1 ? c0 : c1;                    // wave-uniform
        for (int j = 0; j < mc; j += 4) {
#pragma unroll
            for (int i = 0; i < 4; ++i) {
                int s = j + i;                         // < ELLK always
                unsigned w = __shfl(rec, hsel + s);    // bpermute, per-lane src
                __half2 v2 = *(const __half2*)(x16 + (size_t)(w >> 15) * HID + hbase);
                float r = (s < cn) ? rbf_of(w) : 0.0f;
                accx = fmaf(__half2float(v2.x), r, accx);
                accy = fmaf(__half2float(v2.y), r, accy);
            }
        }
        __half2 o;
        o.x = __float2half(accx);
        o.y = __float2half(accy);
        if (!hsel || two)
            *(__half2*)(y16 + (size_t)myn * HID + hbase) = o;
    }
}

// MFMA linear (layouts HW-verified): out = relu(Y·Wᵀ + b), 16-node×64-h
// tile/wave, mfma_f32_16x16x32_f16. A-frags load directly from fp16 y16;
// writes fp16 x16 for the next layer; fp32 d_out only on the final layer.
__global__ void linear_kernel(const __half* __restrict__ y16, const float* __restrict__ W,
                              const float* __restrict__ b, float* __restrict__ out32,
                              __half* __restrict__ out16, int n) {
    int lane = threadIdx.x & 63;
    int r16 = lane & 15;
    int quad = lane >> 4;
    int wid = (blockIdx.x * blockDim.x + threadIdx.x) >> 6;
    int nw = (gridDim.x * blockDim.x) >> 6;

    half8 bfrag[4][2];
    float biasv[4];
#pragma unroll
    for (int ht = 0; ht < 4; ++ht) {
#pragma unroll
        for (int kt = 0; kt < 2; ++kt) {
            const float* src = W + (ht * 16 + r16) * HID + kt * 32 + quad * 8;
            half8 h;
#pragma unroll
            for (int j = 0; j < 8; ++j) h[j] = (_Float16)src[j];
            bfrag[ht][kt] = h;
        }
        biasv[ht] = b[ht * 16 + r16];
    }

    int ntiles = (n + 15) >> 4;
    for (int t = wid; t < ntiles; t += nw) {
        int base = t << 4;
        int arow = base + r16;
        if (arow >= n) arow = n - 1;              // tail clamp (loads only)
        const __half* yr = y16 + (size_t)arow * HID + quad * 8;
        half8 afrag0 = *(const half8*)(yr);
        half8 afrag1 = *(const half8*)(yr + 32);
#pragma unroll
        for (int ht = 0; ht < 4; ++ht) {
            f32x4 acc = {biasv[ht], biasv[ht], biasv[ht], biasv[ht]};
            acc = __builtin_amdgcn_mfma_f32_16x16x32_f16(afrag0, bfrag[ht][0], acc, 0, 0, 0);
            acc = __builtin_amdgcn_mfma_f32_16x16x32_f16(afrag1, bfrag[ht][1], acc, 0, 0, 0);
#pragma unroll
            for (int r = 0; r < 4; ++r) {
                int row = base + quad * 4 + r;
                if (row < n) {
                    float v = fmaxf(acc[r], 0.0f);
                    size_t idx = (size_t)row * HID + ht * 16 + r16;
                    if (out32) out32[idx] = v;
                    if (out16) out16[idx] = __float2half(v);
                }
            }
        }
    }
}

extern "C" void kernel_launch(void* const* d_in, const int* in_sizes, int n_in,
                              void* d_out, int out_size, void* d_ws, size_t ws_size,
                              hipStream_t stream) {
    const int*   z    = (const int*)d_in[0];
    const float* pos  = (const float*)d_in[1];
    const int*   eidx = (const int*)d_in[2];
    const float* emb  = (const float*)d_in[3];
    const float* Ws   = (const float*)d_in[4];
    const float* bs   = (const float*)d_in[5];
    int n = in_sizes[0];
    int e = in_sizes[2] / 2;
    int nlayers = in_sizes[4] / (HID * HID);
    const int* row = eidx;
    const int* col = eidx + e;
    float* out = (float*)d_out;

    char* ws = (char*)d_ws;
    __half*   X16 = (__half*)ws;                                   // n*64 fp16 (12.8 MB)
    __half*   Y16 = X16 + (size_t)n * HID;                         // n*64 fp16 (12.8 MB)
    unsigned* ell = (unsigned*)((char*)Y16 + (size_t)n * HID * 2); // (n+2)*ELLK u32
    int*      cnt = (int*)((char*)ell + (size_t)(n + 2) * ELLK * 4); // n+1 ints

    // 8 dispatches: embed(+cnt zero), fill, 3x(gather, linear)
    embed_kernel<<<(n * HID / 2 + 255) / 256, 256, 0, stream>>>(z, emb, X16, cnt, n);
    fill_kernel<<<(e + 255) / 256, 256, 0, stream>>>(row, col, pos, cnt, ell, e);

    for (int l = 0; l < nlayers; ++l) {
        bool last = (l == nlayers - 1);
        gather_kernel<<<2048, 256, 0, stream>>>(X16, cnt, ell, Y16, n);
        linear_kernel<<<1024, 256, 0, stream>>>(Y16, Ws + (size_t)l * HID * HID,
                                                bs + (size_t)l * HID,
                                                last ? out : nullptr,
                                                last ? nullptr : X16, n);
    }
}

// Round 17
// 208.483 us; speedup vs baseline: 1.2101x; 1.0141x over previous
//
#include <hip/hip_runtime.h>
#include <hip/hip_fp16.h>

#define HID 64
#define ELLK 32   // slots/node; kept degree ~Poisson(5.5), max over 100k ~18
#define CUT_D2 132.5471f   // drop rbf < 1e-5 (R10: measured no absmax change)

typedef _Float16 half8 __attribute__((ext_vector_type(8)));
typedef float f32x4 __attribute__((ext_vector_type(4)));

__device__ __forceinline__ float rbf_of(unsigned w) {
    return __half2float(__ushort_as_half((unsigned short)(w & 0x7fff)));
}

// x16[n][h] = fp16(emb[z[n]][h]); also zeroes ELL counters (rides this kernel).
__global__ void embed_kernel(const int* __restrict__ z, const float* __restrict__ emb,
                             __half* __restrict__ x16, int* __restrict__ cnt, int n) {
    int t = blockIdx.x * blockDim.x + threadIdx.x;
    if (t <= n) cnt[t] = 0;
    if (t >= n * HID / 2) return;
    int node = t >> 5, h2 = (t & 31) * 2;
    const float* src = emb + z[node] * HID + h2;
    __half2 v;
    v.x = __float2half(src[0]);
    v.y = __float2half(src[1]);
    *(__half2*)(x16 + (size_t)node * HID + h2) = v;
}

// ELL fill + fused rbf for KEPT edges; packed record (col<<15)|fp16(rbf).
__global__ void fill_kernel(const int* __restrict__ row, const int* __restrict__ col,
                            const float* __restrict__ pos, int* __restrict__ cnt,
                            unsigned* __restrict__ ell, int e) {
    int t = blockIdx.x * blockDim.x + threadIdx.x;
    if (t >= e) return;
    int r = row[t], c = col[t];
    float dx = pos[3 * r]     - pos[3 * c];
    float dy = pos[3 * r + 1] - pos[3 * c + 1];
    float dz = pos[3 * r + 2] - pos[3 * c + 2];
    float d2 = dx * dx + dy * dy + dz * dz;
    if (d2 > CUT_D2) return;
    float rbf = expf(-sqrtf(d2));
    unsigned short hb = __half_as_ushort(__float2half(rbf));
    int p = atomicAdd(&cnt[r], 1);
    if (p < ELLK) ell[(size_t)r * ELLK + p] = ((unsigned)c << 15) | (unsigned)hb;
}

// y16[n] = fp16( x16[n] + sum_slots x16[col]*rbf ) — TWO nodes per wave,
// half2 lane mapping (R15, proven). R17 deltas, surgical:
//  (1) chunk depth 8 (was 4): 8 independent row loads in flight per chunk —
//      2x MLP against the ~300cyc L3 latency that bounds this kernel. Overshoot
//      slots (mc>8 in ~28% of pairs) are exact no-ops via (2).
//  (2) producer-side pre-mask: each lane zeroes its own slot's rbf bits when
//      slot >= cnt(its node), removing the per-slot compare/select. Masked and
//      overshoot slots contribute fmaf(v, 0.0f, acc) == acc exactly (poison
//      cols decode to <n, loads are valid) -> bit-identical to R15.
__global__ void gather_kernel(const __half* __restrict__ x16, const int* __restrict__ cnt,
                              const unsigned* __restrict__ ell,
                              __half* __restrict__ y16, int n) {
    int lane = threadIdx.x & 63;
    int hsel = lane & 32;              // 0: node n0 lanes, 32: node n0+1 lanes
    int hbase = (lane & 31) * 2;       // h pair handled by this lane
    int wid = (blockIdx.x * blockDim.x + threadIdx.x) >> 6;
    int nw = (gridDim.x * blockDim.x) >> 6;
    int npair = (n + 1) >> 1;
    for (int p = wid; p < npair; p += nw) {
        int n0 = __builtin_amdgcn_readfirstlane(2 * p);
        bool two = (n0 + 1 < n);
        int c0 = cnt[n0]; if (c0 > ELLK) c0 = ELLK;
        int c1 = two ? cnt[n0 + 1] : 0; if (c1 > ELLK) c1 = ELLK;
        int myn = (hsel && two) ? (n0 + 1) : n0;       // row owned by this lane
        unsigned rec = ell[(size_t)n0 * ELLK + lane];  // lane = slot (both nodes)
        int cm = hsel ? c1 : c0;                       // count of THIS lane's node
        if ((lane & 31) >= cm) rec &= 0xFFFF8000u;     // pre-mask: zero rbf bits
        __half2 res = *(const __half2*)(x16 + (size_t)myn * HID + hbase);
        float accx = __half2float(res.x);
        float accy = __half2float(res.y);
        int mc = c0 > c1 ? c0 : c1;                    // wave-uniform
        for (int j = 0; j < mc; j += 8) {
#pragma unroll
            for (int i = 0; i < 8; ++i) {
                int s = j + i;                         // < ELLK always (mc<=32)
                unsigned w = __shfl(rec, hsel + s);    // bpermute, per-lane src
                __half2 v2 = *(const __half2*)(x16 + (size_t)(w >> 15) * HID + hbase);
                float r = rbf_of(w);                   // pre-masked: 0 if dead slot
                accx = fmaf(__half2float(v2.x), r, accx);
                accy = fmaf(__half2float(v2.y), r, accy);
            }
        }
        __half2 o;
        o.x = __float2half(accx);
        o.y = __float2half(accy);
        if (!hsel || two)
            *(__half2*)(y16 + (size_t)myn * HID + hbase) = o;
    }
}

// MFMA linear (layouts HW-verified): out = relu(Y·Wᵀ + b), 16-node×64-h
// tile/wave, mfma_f32_16x16x32_f16. A-frags load directly from fp16 y16;
// writes fp16 x16 for the next layer; fp32 d_out only on the final layer.
__global__ void linear_kernel(const __half* __restrict__ y16, const float* __restrict__ W,
                              const float* __restrict__ b, float* __restrict__ out32,
                              __half* __restrict__ out16, int n) {
    int lane = threadIdx.x & 63;
    int r16 = lane & 15;
    int quad = lane >> 4;
    int wid = (blockIdx.x * blockDim.x + threadIdx.x) >> 6;
    int nw = (gridDim.x * blockDim.x) >> 6;

    half8 bfrag[4][2];
    float biasv[4];
#pragma unroll
    for (int ht = 0; ht < 4; ++ht) {
#pragma unroll
        for (int kt = 0; kt < 2; ++kt) {
            const float* src = W + (ht * 16 + r16) * HID + kt * 32 + quad * 8;
            half8 h;
#pragma unroll
            for (int j = 0; j < 8; ++j) h[j] = (_Float16)src[j];
            bfrag[ht][kt] = h;
        }
        biasv[ht] = b[ht * 16 + r16];
    }

    int ntiles = (n + 15) >> 4;
    for (int t = wid; t < ntiles; t += nw) {
        int base = t << 4;
        int arow = base + r16;
        if (arow >= n) arow = n - 1;              // tail clamp (loads only)
        const __half* yr = y16 + (size_t)arow * HID + quad * 8;
        half8 afrag0 = *(const half8*)(yr);
        half8 afrag1 = *(const half8*)(yr + 32);
#pragma unroll
        for (int ht = 0; ht < 4; ++ht) {
            f32x4 acc = {biasv[ht], biasv[ht], biasv[ht], biasv[ht]};
            acc = __builtin_amdgcn_mfma_f32_16x16x32_f16(afrag0, bfrag[ht][0], acc, 0, 0, 0);
            acc = __builtin_amdgcn_mfma_f32_16x16x32_f16(afrag1, bfrag[ht][1], acc, 0, 0, 0);
#pragma unroll
            for (int r = 0; r < 4; ++r) {
                int row = base + quad * 4 + r;
                if (row < n) {
                    float v = fmaxf(acc[r], 0.0f);
                    size_t idx = (size_t)row * HID + ht * 16 + r16;
                    if (out32) out32[idx] = v;
                    if (out16) out16[idx] = __float2half(v);
                }
            }
        }
    }
}

extern "C" void kernel_launch(void* const* d_in, const int* in_sizes, int n_in,
                              void* d_out, int out_size, void* d_ws, size_t ws_size,
                              hipStream_t stream) {
    const int*   z    = (const int*)d_in[0];
    const float* pos  = (const float*)d_in[1];
    const int*   eidx = (const int*)d_in[2];
    const float* emb  = (const float*)d_in[3];
    const float* Ws   = (const float*)d_in[4];
    const float* bs   = (const float*)d_in[5];
    int n = in_sizes[0];
    int e = in_sizes[2] / 2;
    int nlayers = in_sizes[4] / (HID * HID);
    const int* row = eidx;
    const int* col = eidx + e;
    float* out = (float*)d_out;

    char* ws = (char*)d_ws;
    __half*   X16 = (__half*)ws;                                   // n*64 fp16 (12.8 MB)
    __half*   Y16 = X16 + (size_t)n * HID;                         // n*64 fp16 (12.8 MB)
    unsigned* ell = (unsigned*)((char*)Y16 + (size_t)n * HID * 2); // (n+2)*ELLK u32
    int*      cnt = (int*)((char*)ell + (size_t)(n + 2) * ELLK * 4); // n+1 ints

    // 8 dispatches: embed(+cnt zero), fill, 3x(gather, linear)
    // (R16 lesson: hipLaunchCooperativeKernel does NOT survive this harness's
    // graph capture — the ~50us of dispatch gaps are structural.)
    embed_kernel<<<(n * HID / 2 + 255) / 256, 256, 0, stream>>>(z, emb, X16, cnt, n);
    fill_kernel<<<(e + 255) / 256, 256, 0, stream>>>(row, col, pos, cnt, ell, e);

    for (int l = 0; l < nlayers; ++l) {
        bool last = (l == nlayers - 1);
        gather_kernel<<<2048, 256, 0, stream>>>(X16, cnt, ell, Y16, n);
        linear_kernel<<<1024, 256, 0, stream>>>(Y16, Ws + (size_t)l * HID * HID,
                                                bs + (size_t)l * HID,
                                                last ? out : nullptr,
                                                last ? nullptr : X16, n);
    }
}